// Round 5
// baseline (215.670 us; speedup 1.0000x reference)
//
#include <hip/hip_runtime.h>
#include <stdint.h>

#define NN 65536
#define NE 262144

typedef __attribute__((ext_vector_type(8))) short bf16x8;
typedef __attribute__((ext_vector_type(4))) float f32x4;

__device__ __forceinline__ short f2bf(float f) {
  union { float f; uint32_t u; } v; v.f = f;
  uint32_t u = v.u + 0x7fffu + ((v.u >> 16) & 1u);
  return (short)(u >> 16);
}
__device__ __forceinline__ uint32_t cvtpk(float lo, float hi) {
  uint32_t r;
  asm("v_cvt_pk_bf16_f32 %0, %1, %2" : "=v"(r) : "v"(lo), "v"(hi));
  return r;
}

// Merged prep: eab[e][k] bf16 (k<16, zero-padded from 10) + transposed bf16 weights
// w1t[n][k] (k<32 zero-padded) = w1[k][n]; w2t[n][k] = w2[k][n]
__global__ __launch_bounds__(256) void prep_all(
    const float* __restrict__ ea, short* __restrict__ eab,
    const float* __restrict__ w1_0, const float* __restrict__ w1_1,
    const float* __restrict__ w2_0, const float* __restrict__ w2_1,
    short* __restrict__ w1t0, short* __restrict__ w1t1,
    short* __restrict__ w2t0, short* __restrict__ w2t1) {
  int idx = blockIdx.x * 256 + threadIdx.x;  // grid = NE*16/256
  {
    int e = idx >> 4, k = idx & 15;
    eab[idx] = (k < 10) ? f2bf(ea[e * 10 + k]) : (short)0;
  }
  if (idx < 65536) {
    if (idx < 8192) {
      int n = idx >> 5, k = idx & 31;
      w1t0[idx] = (k < 10) ? f2bf(w1_0[k * 256 + n]) : (short)0;
      w1t1[idx] = (k < 10) ? f2bf(w1_1[k * 256 + n]) : (short)0;
    }
    if (idx < 32768) {
      int n = idx >> 8, k = idx & 255;
      w2t1[idx] = f2bf(w2_1[k * 128 + n]);
    }
    {
      int n = idx >> 8, k = idx & 255;
      w2t0[idx] = f2bf(w2_0[k * 256 + n]);
    }
  }
}

// Fused per-layer edge kernel: 128 edges/block, 8 waves.
// GEMM1 swapped (A=w1t, B=ea^T): wave w computes h cols [w*32,+32) for all 128
// edges; packed cvt_pk + ds_write_b64 h-stores into XOR-swizzled hB.
// GEMM2: wave w owns output cols [w*WCOLS,+WCOLS) across ALL 8 e-tiles
// (B-frag shared by 8 MFMAs; per-edge w2t traffic halved vs 4-wave version).
template <int N2, int OUTC, bool DO_CNT>
__global__ __launch_bounds__(512, 4) void edge_kernel(
    const float* __restrict__ x, const int* __restrict__ ei,
    const short* __restrict__ eab, const short* __restrict__ w1t,
    const float* __restrict__ b1, const short* __restrict__ w2t,
    const float* __restrict__ b2, float* __restrict__ ssum,
    float* __restrict__ cnt) {
  constexpr int WCOLS = N2 / 8;                 // 32 / 16
  constexpr int NT2 = WCOLS / 16;               // 2 / 1
  constexpr int LOGO = (OUTC == 16) ? 4 : 3;
  constexpr int PADO = OUTC + 1;                // 17 / 9
  constexpr int PARTSZ = 8 * 128 * PADO * 4;    // 69632 / 36864
  constexpr int XSOFF = (PARTSZ > 65536) ? PARTSZ : 65536;
  __shared__ alignas(16) char smem[XSOFF + 128 * 20 * 4];
  char* const hB = smem;                        // h [128 e][256 k] bf16, XOR-swz
  float* const partial = (float*)smem;          // overlays hB after GEMM2
  float* const xs = (float*)(smem + XSOFF);     // x[src] [128][20] f32

  const int tid = threadIdx.x;
  const int w = tid >> 6;
  const int lane = tid & 63;
  const int g = lane >> 4;
  const int lr = lane & 15;
  const int e0 = blockIdx.x * 128;

  // ---- preload edge indices + stage x[src] tile [128][20] f32 ----
  const int eR = tid >> 2;
  const int qR = tid & 3;
  const int dR = ei[NE + e0 + eR];   // dst, used in final reduce
  {
    int s = ei[e0 + eR];
    float4 v = *(const float4*)(x + (size_t)s * 16 + qR * 4);
    *(float4*)(xs + eR * 20 + qR * 4) = v;
  }

  // ---- GEMM1 frags ----
  bf16x8 aw[2];  // A = w1t rows n=(w*2+ml)*16+lr, k contiguous
#pragma unroll
  for (int ml = 0; ml < 2; ++ml)
    aw[ml] = *(const bf16x8*)(w1t + ((w * 2 + ml) * 16 + lr) * 32 + g * 8);
  bf16x8 be[8];  // B = ea^T cols e=et*16+lr (k>=16 zero)
#pragma unroll
  for (int et = 0; et < 8; ++et) {
    if (g < 2)
      be[et] = *(const bf16x8*)(eab + (size_t)(e0 + et * 16 + lr) * 16 + g * 8);
    else
      be[et] = (bf16x8){0, 0, 0, 0, 0, 0, 0, 0};
  }

  // ---- GEMM1: acc1[ml][et] = h[n=(w*2+ml)*16+g*4+r][e=et*16+lr] ----
  f32x4 acc1[2][8];
#pragma unroll
  for (int ml = 0; ml < 2; ++ml)
#pragma unroll
    for (int et = 0; et < 8; ++et) acc1[ml][et] = (f32x4){0.f, 0.f, 0.f, 0.f};
#pragma unroll
  for (int et = 0; et < 8; ++et)
#pragma unroll
    for (int ml = 0; ml < 2; ++ml)
      acc1[ml][et] = __builtin_amdgcn_mfma_f32_16x16x32_bf16(aw[ml], be[et], acc1[ml][et], 0, 0, 0);

  // ---- GEMM2 B-frags for ks=0: issue early, hide under h-store ----
  bf16x8 bcur[NT2];
#pragma unroll
  for (int nt = 0; nt < NT2; ++nt) {
    int colo = w * WCOLS + nt * 16 + lr;
    bcur[nt] = *(const bf16x8*)(w2t + colo * 256 + g * 8);
  }

  // ---- h = relu(+b1) -> hB, cvt_pk + ds_write_b64 ----
#pragma unroll
  for (int ml = 0; ml < 2; ++ml) {
    int kb = (w * 2 + ml) * 16 + g * 4;
    float4 bb = *(const float4*)(b1 + kb);
#pragma unroll
    for (int et = 0; et < 8; ++et) {
      int e = et * 16 + lr;
      float v0 = fmaxf(acc1[ml][et][0] + bb.x, 0.f);
      float v1 = fmaxf(acc1[ml][et][1] + bb.y, 0.f);
      float v2 = fmaxf(acc1[ml][et][2] + bb.z, 0.f);
      float v3 = fmaxf(acc1[ml][et][3] + bb.w, 0.f);
      int2 pw; pw.x = (int)cvtpk(v0, v1); pw.y = (int)cvtpk(v2, v3);
      *(int2*)(hB + ((e * 512 + kb * 2) ^ ((e & 7) << 4))) = pw;
    }
  }
  __syncthreads();

  // ---- GEMM2: acc[mt][nt] over all 8 e-tiles, B prefetch depth 1 ----
  f32x4 acc[8][NT2];
#pragma unroll
  for (int mt = 0; mt < 8; ++mt)
#pragma unroll
    for (int nt = 0; nt < NT2; ++nt) acc[mt][nt] = (f32x4){0.f, 0.f, 0.f, 0.f};
#pragma unroll
  for (int ks = 0; ks < 8; ++ks) {
    bf16x8 bnxt[NT2];
    if (ks < 7) {
#pragma unroll
      for (int nt = 0; nt < NT2; ++nt) {
        int colo = w * WCOLS + nt * 16 + lr;
        bnxt[nt] = *(const bf16x8*)(w2t + colo * 256 + (ks + 1) * 32 + g * 8);
      }
    }
    // a2 in two halves of 4 e-tiles to cap register liveness
#pragma unroll
    for (int hf = 0; hf < 2; ++hf) {
      bf16x8 a2[4];
#pragma unroll
      for (int m4 = 0; m4 < 4; ++m4) {
        int e = (hf * 4 + m4) * 16 + lr;
        a2[m4] = *(const bf16x8*)(hB + ((e * 512 + ks * 64 + g * 16) ^ ((e & 7) << 4)));
      }
#pragma unroll
      for (int nt = 0; nt < NT2; ++nt)
#pragma unroll
        for (int m4 = 0; m4 < 4; ++m4)
          acc[hf * 4 + m4][nt] =
              __builtin_amdgcn_mfma_f32_16x16x32_bf16(a2[m4], bcur[nt], acc[hf * 4 + m4][nt], 0, 0, 0);
    }
    if (ks < 7) {
#pragma unroll
      for (int nt = 0; nt < NT2; ++nt) bcur[nt] = bnxt[nt];
    }
  }
  __syncthreads();  // all hB reads done -> partial may overlay

  // ---- epilogue: bilinear in registers, write f32 partial per (slot=w,e,o) ----
  {
    const int o = lr & (OUTC - 1);
    float b2c[NT2];
    int iv[NT2];
#pragma unroll
    for (int nt = 0; nt < NT2; ++nt) {
      int colo = w * WCOLS + nt * 16 + lr;
      b2c[nt] = b2[colo];
      iv[nt] = colo >> LOGO;
    }
#pragma unroll
    for (int mt = 0; mt < 8; ++mt)
#pragma unroll
      for (int r = 0; r < 4; ++r) {
        int e = mt * 16 + g * 4 + r;
        float m = 0.f;
#pragma unroll
        for (int nt = 0; nt < NT2; ++nt)
          m += (acc[mt][nt][r] + b2c[nt]) * xs[e * 20 + iv[nt]];
        if (OUTC == 8) m += __shfl_xor(m, 8, 64);  // sum lr-halves (i parity)
        partial[((size_t)w * 128 + e) * PADO + o] = m;
      }
  }
  __syncthreads();

  // ---- cross-slot reduce + atomic scatter ----
  if (qR * 4 < OUTC) {
#pragma unroll
    for (int j = 0; j < 4; ++j) {
      int o = qR * 4 + j;
      float s = 0.f;
#pragma unroll
      for (int sl = 0; sl < 8; ++sl) s += partial[((size_t)sl * 128 + eR) * PADO + o];
      atomicAdd(&ssum[(size_t)dR * OUTC + o], s);
    }
  }
  if (DO_CNT && tid < 128) atomicAdd(&cnt[ei[NE + e0 + tid]], 1.0f);
}

// x_out = relu(ssum/max(cnt,1) + x_in @ root + bias), one thread per node
template <int OUTC>
__global__ __launch_bounds__(256) void node_kernel(
    const float* __restrict__ xin, const float* __restrict__ ssum,
    const float* __restrict__ cnt, const float* __restrict__ root,
    const float* __restrict__ bias, float* __restrict__ xout) {
  int n = blockIdx.x * 256 + threadIdx.x;
  float inv = 1.0f / fmaxf(cnt[n], 1.0f);
  float xi[16];
#pragma unroll
  for (int i = 0; i < 4; ++i) {
    float4 v = ((const float4*)(xin + (size_t)n * 16))[i];
    xi[4 * i] = v.x; xi[4 * i + 1] = v.y; xi[4 * i + 2] = v.z; xi[4 * i + 3] = v.w;
  }
#pragma unroll
  for (int o = 0; o < OUTC; ++o) {
    float a = ssum[(size_t)n * OUTC + o] * inv + bias[o];
#pragma unroll
    for (int i = 0; i < 16; ++i) a += xi[i] * root[i * OUTC + o];
    xout[(size_t)n * OUTC + o] = fmaxf(a, 0.f);
  }
}

__global__ __launch_bounds__(256) void final_kernel(
    const float* __restrict__ x2, const int* __restrict__ ei,
    const float* __restrict__ fcw, const float* __restrict__ fcb,
    float* __restrict__ out) {
  int e = blockIdx.x * 256 + threadIdx.x;
  int s = ei[e], d = ei[NE + e];
  float acc = fcb[0];
  const float* xsr = x2 + (size_t)s * 8;
  const float* xdr = x2 + (size_t)d * 8;
#pragma unroll
  for (int c = 0; c < 8; ++c) acc += xsr[c] * fcw[c];
#pragma unroll
  for (int c = 0; c < 8; ++c) acc += xdr[c] * fcw[8 + c];
  out[e] = 1.0f / (1.0f + __expf(-acc));
}

extern "C" void kernel_launch(void* const* d_in, const int* in_sizes, int n_in,
                              void* d_out, int out_size, void* d_ws, size_t ws_size,
                              hipStream_t stream) {
  const float* x      = (const float*)d_in[0];
  const int*   ei     = (const int*)d_in[1];
  const float* ea     = (const float*)d_in[2];
  const float* w1_0   = (const float*)d_in[3];
  const float* b1_0   = (const float*)d_in[4];
  const float* w2_0   = (const float*)d_in[5];
  const float* b2_0   = (const float*)d_in[6];
  const float* root_0 = (const float*)d_in[7];
  const float* bias_0 = (const float*)d_in[8];
  const float* w1_1   = (const float*)d_in[9];
  const float* b1_1   = (const float*)d_in[10];
  const float* w2_1   = (const float*)d_in[11];
  const float* b2_1   = (const float*)d_in[12];
  const float* root_1 = (const float*)d_in[13];
  const float* bias_1 = (const float*)d_in[14];
  const float* fc_w   = (const float*)d_in[15];
  const float* fc_b   = (const float*)d_in[16];
  float* out = (float*)d_out;

  char* ws = (char*)d_ws;
  float* ssum0 = (float*)(ws);                         // 4 MB
  float* x1    = (float*)(ws + (4u << 20));            // 4 MB
  float* ssum1 = (float*)(ws + (8u << 20));            // 2 MB
  float* x2    = (float*)(ws + (10u << 20));           // 2 MB
  float* cnt   = (float*)(ws + (12u << 20));           // 256 KB
  short* w1t0  = (short*)(ws + (12u << 20) + (256u << 10));
  short* w1t1  = w1t0 + 8192;
  short* w2t0  = w1t1 + 8192;
  short* w2t1  = w2t0 + 65536;
  short* eab   = w2t1 + 32768;                         // 8 MB

  hipMemsetAsync(ssum0, 0, (size_t)NN * 16 * 4, stream);
  hipMemsetAsync(ssum1, 0, (size_t)NN * 8 * 4, stream);
  hipMemsetAsync(cnt, 0, (size_t)NN * 4, stream);
  prep_all<<<NE * 16 / 256, 256, 0, stream>>>(ea, eab, w1_0, w1_1, w2_0, w2_1,
                                              w1t0, w1t1, w2t0, w2t1);

  edge_kernel<256, 16, true><<<NE / 128, 512, 0, stream>>>(
      x, ei, eab, w1t0, b1_0, w2t0, b2_0, ssum0, cnt);
  node_kernel<16><<<NN / 256, 256, 0, stream>>>(x, ssum0, cnt, root_0, bias_0, x1);
  edge_kernel<128, 8, false><<<NE / 128, 512, 0, stream>>>(
      x1, ei, eab, w1t1, b1_1, w2t1, b2_1, ssum1, nullptr);
  node_kernel<8><<<NN / 256, 256, 0, stream>>>(x1, ssum1, cnt, root_1, bias_1, x2);
  final_kernel<<<NE / 256, 256, 0, stream>>>(x2, ei, fc_w, fc_b, out);
}

// Round 6
// 179.793 us; speedup vs baseline: 1.1995x; 1.1995x over previous
//
#include <hip/hip_runtime.h>
#include <stdint.h>

#define NN 65536
#define NE 262144

typedef __attribute__((ext_vector_type(8))) short bf16x8;
typedef __attribute__((ext_vector_type(4))) float f32x4;

__device__ __forceinline__ short f2bf(float f) {
  union { float f; uint32_t u; } v; v.f = f;
  uint32_t u = v.u + 0x7fffu + ((v.u >> 16) & 1u);
  return (short)(u >> 16);
}
__device__ __forceinline__ uint32_t cvtpk(float lo, float hi) {
  uint32_t r;
  asm("v_cvt_pk_bf16_f32 %0, %1, %2" : "=v"(r) : "v"(lo), "v"(hi));
  return r;
}

// Merged prep: eab[e][k] bf16 (k<16, zero-padded from 10) + transposed bf16 weights
__global__ __launch_bounds__(256) void prep_all(
    const float* __restrict__ ea, short* __restrict__ eab,
    const float* __restrict__ w1_0, const float* __restrict__ w1_1,
    const float* __restrict__ w2_0, const float* __restrict__ w2_1,
    short* __restrict__ w1t0, short* __restrict__ w1t1,
    short* __restrict__ w2t0, short* __restrict__ w2t1) {
  int idx = blockIdx.x * 256 + threadIdx.x;  // grid = NE*16/256
  {
    int e = idx >> 4, k = idx & 15;
    eab[idx] = (k < 10) ? f2bf(ea[e * 10 + k]) : (short)0;
  }
  if (idx < 65536) {
    if (idx < 8192) {
      int n = idx >> 5, k = idx & 31;
      w1t0[idx] = (k < 10) ? f2bf(w1_0[k * 256 + n]) : (short)0;
      w1t1[idx] = (k < 10) ? f2bf(w1_1[k * 256 + n]) : (short)0;
    }
    if (idx < 32768) {
      int n = idx >> 8, k = idx & 255;
      w2t1[idx] = f2bf(w2_1[k * 128 + n]);
    }
    {
      int n = idx >> 8, k = idx & 255;
      w2t0[idx] = f2bf(w2_0[k * 256 + n]);
    }
  }
}

// ---------------- CSR build ----------------
__global__ __launch_bounds__(256) void hist_kernel(const int* __restrict__ ei,
                                                   int* __restrict__ cnt32) {
  int e = blockIdx.x * 256 + threadIdx.x;
  atomicAdd(&cnt32[ei[NE + e]], 1);
}

__global__ __launch_bounds__(256) void scan1_kernel(const int* __restrict__ cnt32,
                                                    int* __restrict__ bsum) {
  __shared__ int sd[256];
  int t = threadIdx.x, b = blockIdx.x;
  sd[t] = cnt32[b * 256 + t];
  __syncthreads();
  for (int s = 128; s > 0; s >>= 1) {
    if (t < s) sd[t] += sd[t + s];
    __syncthreads();
  }
  if (t == 0) bsum[b] = sd[0];
}

__global__ __launch_bounds__(256) void scan2_kernel(const int* __restrict__ bsum,
                                                    int* __restrict__ boff) {
  __shared__ int sd[256];
  int t = threadIdx.x;
  int v = bsum[t];
  sd[t] = v;
  __syncthreads();
  for (int st = 1; st < 256; st <<= 1) {
    int x = (t >= st) ? sd[t - st] : 0;
    __syncthreads();
    sd[t] += x;
    __syncthreads();
  }
  boff[t] = sd[t] - v;  // exclusive
}

__global__ __launch_bounds__(256) void scan3_kernel(const int* __restrict__ cnt32,
                                                    const int* __restrict__ boff,
                                                    int* __restrict__ off) {
  __shared__ int sd[256];
  int t = threadIdx.x, b = blockIdx.x;
  int idx = b * 256 + t;
  int v = cnt32[idx];
  sd[t] = v;
  __syncthreads();
  for (int st = 1; st < 256; st <<= 1) {
    int x = (t >= st) ? sd[t - st] : 0;
    __syncthreads();
    sd[t] += x;
    __syncthreads();
  }
  off[idx] = boff[b] + sd[t] - v;
  if (b == 255 && t == 255) off[65536] = boff[255] + sd[255];
}

__global__ __launch_bounds__(256) void scatter_kernel(const int* __restrict__ ei,
                                                      int* __restrict__ cursor,
                                                      int* __restrict__ eidx) {
  int e = blockIdx.x * 256 + threadIdx.x;
  int pos = atomicAdd(&cursor[ei[NE + e]], 1);
  eidx[pos] = e;
}

// ---------------- fused edge kernel (128 edges/block, 8 waves) ----------------
// GEMM1 swapped (A=w1t, B=ea^T); GEMM2 wave owns WCOLS output cols over all 8
// e-tiles, B-frags from global (L2) with depth-1 prefetch.
// Output: msg[e][o] f32, coalesced store (NO atomics).
template <int N2, int OUTC>
__global__ __launch_bounds__(512, 4) void edge_kernel(
    const float* __restrict__ x, const int* __restrict__ ei,
    const short* __restrict__ eab, const short* __restrict__ w1t,
    const float* __restrict__ b1, const short* __restrict__ w2t,
    const float* __restrict__ b2, float* __restrict__ msg) {
  constexpr int WCOLS = N2 / 8;                 // 32 / 16
  constexpr int NT2 = WCOLS / 16;               // 2 / 1
  constexpr int LOGO = (OUTC == 16) ? 4 : 3;
  constexpr int PADO = OUTC + 1;                // 17 / 9
  constexpr int PARTSZ = 8 * 128 * PADO * 4;    // 69632 / 36864
  constexpr int XSOFF = (PARTSZ > 65536) ? PARTSZ : 65536;
  __shared__ alignas(16) char smem[XSOFF + 128 * 20 * 4];
  char* const hB = smem;                        // h [128 e][256 k] bf16, XOR-swz
  float* const partial = (float*)smem;          // overlays hB after GEMM2
  float* const xs = (float*)(smem + XSOFF);     // x[src] [128][20] f32

  const int tid = threadIdx.x;
  const int w = tid >> 6;
  const int lane = tid & 63;
  const int g = lane >> 4;
  const int lr = lane & 15;
  const int e0 = blockIdx.x * 128;

  // ---- stage x[src] tile [128][20] f32 ----
  const int eR = tid >> 2;
  const int qR = tid & 3;
  {
    int s = ei[e0 + eR];
    float4 v = *(const float4*)(x + (size_t)s * 16 + qR * 4);
    *(float4*)(xs + eR * 20 + qR * 4) = v;
  }

  // ---- GEMM1 frags ----
  bf16x8 aw[2];
#pragma unroll
  for (int ml = 0; ml < 2; ++ml)
    aw[ml] = *(const bf16x8*)(w1t + ((w * 2 + ml) * 16 + lr) * 32 + g * 8);
  bf16x8 be[8];
#pragma unroll
  for (int et = 0; et < 8; ++et) {
    if (g < 2)
      be[et] = *(const bf16x8*)(eab + (size_t)(e0 + et * 16 + lr) * 16 + g * 8);
    else
      be[et] = (bf16x8){0, 0, 0, 0, 0, 0, 0, 0};
  }

  // ---- GEMM1: acc1[ml][et] = h[k=(w*2+ml)*16+g*4+r][e=et*16+lr] ----
  f32x4 acc1[2][8];
#pragma unroll
  for (int ml = 0; ml < 2; ++ml)
#pragma unroll
    for (int et = 0; et < 8; ++et) acc1[ml][et] = (f32x4){0.f, 0.f, 0.f, 0.f};
#pragma unroll
  for (int et = 0; et < 8; ++et)
#pragma unroll
    for (int ml = 0; ml < 2; ++ml)
      acc1[ml][et] = __builtin_amdgcn_mfma_f32_16x16x32_bf16(aw[ml], be[et], acc1[ml][et], 0, 0, 0);

  // ---- GEMM2 ks=0 B-frags: issue early ----
  bf16x8 bcur[NT2];
#pragma unroll
  for (int nt = 0; nt < NT2; ++nt) {
    int colo = w * WCOLS + nt * 16 + lr;
    bcur[nt] = *(const bf16x8*)(w2t + colo * 256 + g * 8);
  }

  // ---- h = relu(+b1) -> hB, cvt_pk + ds_write_b64 ----
#pragma unroll
  for (int ml = 0; ml < 2; ++ml) {
    int kb = (w * 2 + ml) * 16 + g * 4;
    float4 bb = *(const float4*)(b1 + kb);
#pragma unroll
    for (int et = 0; et < 8; ++et) {
      int e = et * 16 + lr;
      float v0 = fmaxf(acc1[ml][et][0] + bb.x, 0.f);
      float v1 = fmaxf(acc1[ml][et][1] + bb.y, 0.f);
      float v2 = fmaxf(acc1[ml][et][2] + bb.z, 0.f);
      float v3 = fmaxf(acc1[ml][et][3] + bb.w, 0.f);
      int2 pw; pw.x = (int)cvtpk(v0, v1); pw.y = (int)cvtpk(v2, v3);
      *(int2*)(hB + ((e * 512 + kb * 2) ^ ((e & 7) << 4))) = pw;
    }
  }
  __syncthreads();

  // ---- GEMM2 over all 8 e-tiles, B prefetch depth 1 ----
  f32x4 acc[8][NT2];
#pragma unroll
  for (int mt = 0; mt < 8; ++mt)
#pragma unroll
    for (int nt = 0; nt < NT2; ++nt) acc[mt][nt] = (f32x4){0.f, 0.f, 0.f, 0.f};
#pragma unroll
  for (int ks = 0; ks < 8; ++ks) {
    bf16x8 bnxt[NT2];
    if (ks < 7) {
#pragma unroll
      for (int nt = 0; nt < NT2; ++nt) {
        int colo = w * WCOLS + nt * 16 + lr;
        bnxt[nt] = *(const bf16x8*)(w2t + colo * 256 + (ks + 1) * 32 + g * 8);
      }
    }
#pragma unroll
    for (int hf = 0; hf < 2; ++hf) {
      bf16x8 a2[4];
#pragma unroll
      for (int m4 = 0; m4 < 4; ++m4) {
        int e = (hf * 4 + m4) * 16 + lr;
        a2[m4] = *(const bf16x8*)(hB + ((e * 512 + ks * 64 + g * 16) ^ ((e & 7) << 4)));
      }
#pragma unroll
      for (int nt = 0; nt < NT2; ++nt)
#pragma unroll
        for (int m4 = 0; m4 < 4; ++m4)
          acc[hf * 4 + m4][nt] =
              __builtin_amdgcn_mfma_f32_16x16x32_bf16(a2[m4], bcur[nt], acc[hf * 4 + m4][nt], 0, 0, 0);
    }
    if (ks < 7) {
#pragma unroll
      for (int nt = 0; nt < NT2; ++nt) bcur[nt] = bnxt[nt];
    }
  }
  __syncthreads();  // all hB reads done -> partial may overlay

  // ---- epilogue: bilinear in registers -> partial[slot=w][e][o] ----
  {
    const int o = lr & (OUTC - 1);
    float b2c[NT2];
    int iv[NT2];
#pragma unroll
    for (int nt = 0; nt < NT2; ++nt) {
      int colo = w * WCOLS + nt * 16 + lr;
      b2c[nt] = b2[colo];
      iv[nt] = colo >> LOGO;
    }
#pragma unroll
    for (int mt = 0; mt < 8; ++mt)
#pragma unroll
      for (int r = 0; r < 4; ++r) {
        int e = mt * 16 + g * 4 + r;
        float m = 0.f;
#pragma unroll
        for (int nt = 0; nt < NT2; ++nt)
          m += (acc[mt][nt][r] + b2c[nt]) * xs[e * 20 + iv[nt]];
        if (OUTC == 8) m += __shfl_xor(m, 8, 64);  // sum lr-halves (i parity)
        partial[((size_t)w * 128 + e) * PADO + o] = m;
      }
  }
  __syncthreads();

  // ---- cross-slot reduce -> coalesced msg store (no atomics) ----
  if (qR * 4 < OUTC) {
    float v[4];
#pragma unroll
    for (int j = 0; j < 4; ++j) {
      int o = qR * 4 + j;
      float s = 0.f;
#pragma unroll
      for (int sl = 0; sl < 8; ++sl) s += partial[((size_t)sl * 128 + eR) * PADO + o];
      v[j] = s;
    }
    *(float4*)(msg + (size_t)(e0 + eR) * OUTC + qR * 4) =
        (float4){v[0], v[1], v[2], v[3]};
  }
}

// x_out = relu(gather-mean(msg over CSR) + x_in @ root + bias)
// thread = (node, output-quad)
template <int OUTC>
__global__ __launch_bounds__(256) void node_csr(
    const float* __restrict__ xin, const float* __restrict__ msg,
    const int* __restrict__ off, const int* __restrict__ eidx,
    const float* __restrict__ root, const float* __restrict__ bias,
    float* __restrict__ xout) {
  constexpr int Q = OUTC / 4;  // 4 / 2
  __shared__ float rootL[16 * OUTC];
  __shared__ float biasL[OUTC];
  int tid = threadIdx.x;
  if (tid < 16 * OUTC) rootL[tid] = root[tid];
  if (tid < OUTC) biasL[tid] = bias[tid];
  __syncthreads();
  int n = blockIdx.x * (256 / Q) + tid / Q;
  int q = tid & (Q - 1);
  int o0 = off[n], o1 = off[n + 1];
  const float4* msg4 = (const float4*)msg;
  float s[4] = {0.f, 0.f, 0.f, 0.f};
  for (int i = o0; i < o1; ++i) {
    int e = eidx[i];
    float4 v = msg4[(size_t)e * Q + q];
    s[0] += v.x; s[1] += v.y; s[2] += v.z; s[3] += v.w;
  }
  float inv = 1.0f / fmaxf((float)(o1 - o0), 1.0f);
  float xi[16];
#pragma unroll
  for (int i = 0; i < 4; ++i) {
    float4 v = ((const float4*)(xin + (size_t)n * 16))[i];
    xi[4 * i] = v.x; xi[4 * i + 1] = v.y; xi[4 * i + 2] = v.z; xi[4 * i + 3] = v.w;
  }
  float r[4];
#pragma unroll
  for (int j = 0; j < 4; ++j) {
    int o = q * 4 + j;
    float a = s[j] * inv + biasL[o];
#pragma unroll
    for (int i = 0; i < 16; ++i) a += xi[i] * rootL[i * OUTC + o];
    r[j] = fmaxf(a, 0.f);
  }
  *(float4*)(xout + (size_t)n * OUTC + q * 4) = (float4){r[0], r[1], r[2], r[3]};
}

__global__ __launch_bounds__(256) void final_kernel(
    const float* __restrict__ x2, const int* __restrict__ ei,
    const float* __restrict__ fcw, const float* __restrict__ fcb,
    float* __restrict__ out) {
  int e = blockIdx.x * 256 + threadIdx.x;
  int s = ei[e], d = ei[NE + e];
  float acc = fcb[0];
  const float* xsr = x2 + (size_t)s * 8;
  const float* xdr = x2 + (size_t)d * 8;
#pragma unroll
  for (int c = 0; c < 8; ++c) acc += xsr[c] * fcw[c];
#pragma unroll
  for (int c = 0; c < 8; ++c) acc += xdr[c] * fcw[8 + c];
  out[e] = 1.0f / (1.0f + __expf(-acc));
}

extern "C" void kernel_launch(void* const* d_in, const int* in_sizes, int n_in,
                              void* d_out, int out_size, void* d_ws, size_t ws_size,
                              hipStream_t stream) {
  const float* x      = (const float*)d_in[0];
  const int*   ei     = (const int*)d_in[1];
  const float* ea     = (const float*)d_in[2];
  const float* w1_0   = (const float*)d_in[3];
  const float* b1_0   = (const float*)d_in[4];
  const float* w2_0   = (const float*)d_in[5];
  const float* b2_0   = (const float*)d_in[6];
  const float* root_0 = (const float*)d_in[7];
  const float* bias_0 = (const float*)d_in[8];
  const float* w1_1   = (const float*)d_in[9];
  const float* b1_1   = (const float*)d_in[10];
  const float* w2_1   = (const float*)d_in[11];
  const float* b2_1   = (const float*)d_in[12];
  const float* root_1 = (const float*)d_in[13];
  const float* bias_1 = (const float*)d_in[14];
  const float* fc_w   = (const float*)d_in[15];
  const float* fc_b   = (const float*)d_in[16];
  float* out = (float*)d_out;

  char* ws = (char*)d_ws;
  int*   off    = (int*)(ws);                          // 65537 ints (~256 KB)
  int*   cursor = (int*)(ws + (512u << 10));           // 256 KB (doubles as cnt32)
  int*   bsum   = (int*)(ws + (1u << 20));             // 1 KB
  int*   boff   = (int*)(ws + (1u << 20) + 4096);      // 1 KB
  short* w1t0   = (short*)(ws + (1u << 20) + 16384);
  short* w1t1   = w1t0 + 8192;
  short* w2t0   = w1t1 + 8192;
  short* w2t1   = w2t0 + 65536;
  float* x1     = (float*)(ws + (2u << 20));           // 4 MB
  float* x2     = (float*)(ws + (6u << 20));           // 2 MB
  int*   eidx   = (int*)(ws + (8u << 20));             // 1 MB
  short* eab    = (short*)(ws + (9u << 20));           // 8 MB
  float* msg    = (float*)(ws + (17u << 20));          // 16 MB (shared L0/L1)

  int* cnt32 = cursor;  // histogram then overwritten... NOTE: scan reads cnt32,
                        // cursor init via memcpy from off AFTER scans.

  hipMemsetAsync(cnt32, 0, (size_t)NN * 4, stream);
  prep_all<<<NE * 16 / 256, 256, 0, stream>>>(ea, eab, w1_0, w1_1, w2_0, w2_1,
                                              w1t0, w1t1, w2t0, w2t1);
  hist_kernel<<<NE / 256, 256, 0, stream>>>(ei, cnt32);
  scan1_kernel<<<256, 256, 0, stream>>>(cnt32, bsum);
  scan2_kernel<<<1, 256, 0, stream>>>(bsum, boff);
  scan3_kernel<<<256, 256, 0, stream>>>(cnt32, boff, off);
  hipMemcpyAsync(cursor, off, (size_t)NN * 4, hipMemcpyDeviceToDevice, stream);
  scatter_kernel<<<NE / 256, 256, 0, stream>>>(ei, cursor, eidx);

  edge_kernel<256, 16><<<NE / 128, 512, 0, stream>>>(
      x, ei, eab, w1t0, b1_0, w2t0, b2_0, msg);
  node_csr<16><<<NN * 4 / 256, 256, 0, stream>>>(x, msg, off, eidx, root_0, bias_0, x1);
  edge_kernel<128, 8><<<NE / 128, 512, 0, stream>>>(
      x1, ei, eab, w1t1, b1_1, w2t1, b2_1, msg);
  node_csr<8><<<NN * 2 / 256, 256, 0, stream>>>(x1, msg, off, eidx, root_1, bias_1, x2);
  final_kernel<<<NE / 256, 256, 0, stream>>>(x2, ei, fc_w, fc_b, out);
}